// Round 8
// baseline (103.989 us; speedup 1.0000x reference)
//
#include <hip/hip_runtime.h>
#include <hip/hip_bf16.h>
#include <stdint.h>

#define DENSE_D 512
#define HIDDEN1 512
#define HIDDEN2 256
#define EMB_D   64
#define NFEAT   7
#define NROWS   9
#define NPAIRS  36
#define COMB    100          // 64 + 36
#define PROJ    128
#define C_CAMP  1000
#define C_FEAT  316
#define NQ_FEAT 317
#define TROWS   16           // rows per tail block
#define HISTMAX 52           // LDS offset-table stride

typedef __attribute__((ext_vector_type(8)))  __bf16 bf16x8;
typedef __attribute__((ext_vector_type(8)))  unsigned short ushort8;
typedef __attribute__((ext_vector_type(4)))  float  facc4;

#define GLD_LDS16(gp, lp) __builtin_amdgcn_global_load_lds( \
    (__attribute__((address_space(1))) void*)(gp), \
    (__attribute__((address_space(3))) void*)(lp), 16, 0, 0)

__device__ inline unsigned short f2bf(float f) {
    __hip_bfloat16 h = __float2bfloat16(f);
    return *reinterpret_cast<unsigned short*>(&h);
}
__device__ inline float blo(unsigned int u) { return __uint_as_float(u << 16); }
__device__ inline float bhi(unsigned int u) { return __uint_as_float(u & 0xffff0000u); }

union bfr8 { bf16x8 v; ushort8 u; };

// ---------------------------------------------------------------------------
// bf16 MFMA GEMM, 16x16x32 frags: C = act(A @ W^T + bias), bf16 out.
// A_F32/B_F32: operand is fp32 in global, cast to bf16 during reg-staging;
// else bf16 via global_load_lds. CAST: also cast camp tables (prologue, 1 pass).
// LDS k-chunk-major [BK/8][R][8].
// ---------------------------------------------------------------------------
template<int BM, int BN, int BK, int WM, int WN, bool RELU,
         bool A_F32, bool B_F32, bool CAST>
__global__ __launch_bounds__(WM * WN * 64)
void gemm16(const void* __restrict__ Avoid,
            const void* __restrict__ Wvoid,
            const float* __restrict__ bias,
            unsigned short* __restrict__ Cout,
            int M, int N, int K,
            const float* __restrict__ qc, const float* __restrict__ rc,
            unsigned short* __restrict__ qcb, unsigned short* __restrict__ rcb)
{
    constexpr int THREADS = WM * WN * 64;
    constexpr int MREP    = BM / (WM * 16);
    constexpr int NREP    = BN / (WN * 16);
    constexpr int SUB     = BK / 32;
    constexpr int ACH     = BM * BK / 8;
    constexpr int BCH     = BN * BK / 8;

    __shared__ __align__(16) unsigned short Asm[BK / 8][BM][8];
    __shared__ __align__(16) unsigned short Bsm[BK / 8][BN][8];

    const int tid  = threadIdx.x;
    const int lane = tid & 63;
    const int wave = tid >> 6;
    const int wm   = wave / WN;
    const int wn   = wave % WN;
    const int row0 = blockIdx.x * BM;
    const int col0 = blockIdx.y * BN;
    const int fr   = lane & 15;
    const int fk   = lane >> 4;

    if (CAST) {
        // camp tables fp32 -> bf16, one float4 per thread (grid covers all)
        constexpr int N4 = C_CAMP * EMB_D / 4;   // 16000 per table
        const int gid = (blockIdx.y * gridDim.x + blockIdx.x) * THREADS + tid;
        if (gid < 2 * N4) {
            const bool second = gid >= N4;
            const int i = second ? gid - N4 : gid;
            const float4 v = reinterpret_cast<const float4*>(second ? rc : qc)[i];
            ushort4 o;
            o.x = f2bf(v.x); o.y = f2bf(v.y); o.z = f2bf(v.z); o.w = f2bf(v.w);
            reinterpret_cast<ushort4*>(second ? rcb : qcb)[i] = o;
        }
    }

    facc4 acc[MREP][NREP] = {};

    for (int k0 = 0; k0 < K; k0 += BK) {
        if (A_F32) {
            const float* Af = (const float*)Avoid;
            #pragma unroll
            for (int it = 0; it < ACH / THREADS; ++it) {
                const int p  = it * THREADS + tid;
                const int r  = p & (BM - 1);
                const int kc = p / BM;
                const float* src = Af + (size_t)(row0 + r) * K + k0 + kc * 8;
                const float4 v0 = *reinterpret_cast<const float4*>(src);
                const float4 v1 = *reinterpret_cast<const float4*>(src + 4);
                ushort8 cv;
                cv[0] = f2bf(v0.x); cv[1] = f2bf(v0.y);
                cv[2] = f2bf(v0.z); cv[3] = f2bf(v0.w);
                cv[4] = f2bf(v1.x); cv[5] = f2bf(v1.y);
                cv[6] = f2bf(v1.z); cv[7] = f2bf(v1.w);
                *reinterpret_cast<ushort8*>(
                    (unsigned short*)(&Asm[0][0][0]) + (size_t)p * 8) = cv;
            }
        } else {
            const unsigned short* Ab = (const unsigned short*)Avoid;
            #pragma unroll
            for (int it = 0; it < ACH / THREADS; ++it) {
                const int p  = it * THREADS + tid;
                const int r  = p & (BM - 1);
                const int kc = p / BM;
                GLD_LDS16(Ab + (size_t)(row0 + r) * K + k0 + kc * 8,
                          (&Asm[0][0][0]) + (size_t)p * 8);
            }
        }
        if (B_F32) {
            const float* Wf = (const float*)Wvoid;
            #pragma unroll
            for (int it = 0; it < BCH / THREADS; ++it) {
                const int p  = it * THREADS + tid;
                const int r  = p & (BN - 1);
                const int kc = p / BN;
                const float* src = Wf + (size_t)(col0 + r) * K + k0 + kc * 8;
                const float4 v0 = *reinterpret_cast<const float4*>(src);
                const float4 v1 = *reinterpret_cast<const float4*>(src + 4);
                ushort8 cv;
                cv[0] = f2bf(v0.x); cv[1] = f2bf(v0.y);
                cv[2] = f2bf(v0.z); cv[3] = f2bf(v0.w);
                cv[4] = f2bf(v1.x); cv[5] = f2bf(v1.y);
                cv[6] = f2bf(v1.z); cv[7] = f2bf(v1.w);
                *reinterpret_cast<ushort8*>(
                    (unsigned short*)(&Bsm[0][0][0]) + (size_t)p * 8) = cv;
            }
        } else {
            const unsigned short* Wb = (const unsigned short*)Wvoid;
            #pragma unroll
            for (int it = 0; it < BCH / THREADS; ++it) {
                const int p  = it * THREADS + tid;
                const int r  = p & (BN - 1);
                const int kc = p / BN;
                GLD_LDS16(Wb + (size_t)(col0 + r) * K + k0 + kc * 8,
                          (&Bsm[0][0][0]) + (size_t)p * 8);
            }
        }
        __syncthreads();

        #pragma unroll
        for (int s = 0; s < SUB; ++s) {
            bf16x8 af[MREP], bw[NREP];
            #pragma unroll
            for (int m = 0; m < MREP; ++m)
                af[m] = *reinterpret_cast<const bf16x8*>(
                    &Asm[s * 4 + fk][wm * (MREP * 16) + m * 16 + fr][0]);
            #pragma unroll
            for (int n = 0; n < NREP; ++n)
                bw[n] = *reinterpret_cast<const bf16x8*>(
                    &Bsm[s * 4 + fk][wn * (NREP * 16) + n * 16 + fr][0]);
            #pragma unroll
            for (int m = 0; m < MREP; ++m)
                #pragma unroll
                for (int n = 0; n < NREP; ++n)
                    acc[m][n] = __builtin_amdgcn_mfma_f32_16x16x32_bf16(
                        af[m], bw[n], acc[m][n], 0, 0, 0);
        }
        __syncthreads();
    }

    // C/D layout: col=lane&15, row=(lane>>4)*4+j  [m89/m91-verified]
    #pragma unroll
    for (int n = 0; n < NREP; ++n) {
        const int col = col0 + wn * (NREP * 16) + n * 16 + fr;
        const float bv = bias[col];
        #pragma unroll
        for (int m = 0; m < MREP; ++m) {
            #pragma unroll
            for (int j = 0; j < 4; ++j) {
                const int row = row0 + wm * (MREP * 16) + m * 16 + fk * 4 + j;
                float v = acc[m][n][j] + bv;
                if (RELU) v = fmaxf(v, 0.f);
                Cout[(size_t)row * N + col] = f2bf(v);
            }
        }
    }
}

// ---------------------------------------------------------------------------
// Fused tail: per block = 16 rows, 512 threads (8 waves).
// Waves 0-3: GEMM2 (h1@W2^T, W2 fp32 inline-cast) then join gather (half 0).
// Waves 4-7: gather immediately (half 1). Each half stages its own soff parity.
// Then interactions -> combs, proj (Wp fp32 inline-cast, kw=3 predicated).
// ---------------------------------------------------------------------------
__global__ __launch_bounds__(512)
void tail_fused(const unsigned short* __restrict__ h1b,
                const float* __restrict__ W2,
                const float* __restrict__ b2,
                const int* __restrict__ hist_idx,
                const int* __restrict__ hist_off,
                const int* __restrict__ feat_idx,
                const unsigned short* __restrict__ qcb,
                const unsigned short* __restrict__ rcb,
                const float* __restrict__ Wq_f,
                const float* __restrict__ Wr_f,
                const float* __restrict__ Wp,
                const float* __restrict__ bp,
                float* __restrict__ out,
                int B, int Mtot)
{
    const int r0   = blockIdx.x * TROWS;
    const int t    = threadIdx.x;       // 512
    const int lane = t & 63;
    const int wave = t >> 6;            // 0..7
    const int fr   = lane & 15;
    const int fk   = lane >> 4;

    __shared__ __align__(16) unsigned short T[TROWS][NROWS][68];
    __shared__ __align__(16) unsigned short combs[TROWS][136];
    __shared__ int2  soff[TROWS][HISTMAX];
    __shared__ float part[TROWS][68];

    // ---- GEMM2 (waves 0-3): 16x64, K=256; wave w -> cols w*16..+15 ----
    if (wave < 4) {
        facc4 acc = {};
        const unsigned short* arow = h1b + (size_t)(r0 + fr) * HIDDEN2;
        const float* brow = W2 + (size_t)(wave * 16 + fr) * HIDDEN2;
        #pragma unroll
        for (int kw = 0; kw < 8; ++kw) {
            const bf16x8 af = *reinterpret_cast<const bf16x8*>(arow + kw * 32 + fk * 8);
            const float4 w0 = *reinterpret_cast<const float4*>(brow + kw * 32 + fk * 8);
            const float4 w1 = *reinterpret_cast<const float4*>(brow + kw * 32 + fk * 8 + 4);
            bfr8 bw;
            bw.u[0] = f2bf(w0.x); bw.u[1] = f2bf(w0.y);
            bw.u[2] = f2bf(w0.z); bw.u[3] = f2bf(w0.w);
            bw.u[4] = f2bf(w1.x); bw.u[5] = f2bf(w1.y);
            bw.u[6] = f2bf(w1.z); bw.u[7] = f2bf(w1.w);
            acc = __builtin_amdgcn_mfma_f32_16x16x32_bf16(af, bw.v, acc, 0, 0, 0);
        }
        const int col = wave * 16 + fr;
        const float bv = b2[col];
        #pragma unroll
        for (int j = 0; j < 4; ++j) {
            const int row = fk * 4 + j;
            const unsigned short hv = f2bf(acc[j] + bv);
            T[row][0][col]  = hv;
            combs[row][col] = hv;
        }
    }

    // zero combs[.][100..135]
    for (int p = t; p < TROWS * 18; p += 512) {
        const int row = p / 18, c = p % 18;
        *reinterpret_cast<unsigned int*>(&combs[row][100 + c * 2]) = 0u;
    }

    // ---- embeddings: 32 threads per row (16 dims-quads x 2 item-halves) ----
    {
        const int row  = (t >> 4) & 15;
        const int oc   = t & 15;
        const int half = t >> 8;         // 0: waves 0-3, 1: waves 4-7
        const int br   = r0 + row;

        // feature embeddings (fp32 tables): half0 f=0..3, half1 f=4..6
        const int fbase = br * NFEAT;
        for (int f = half ? 4 : 0; f < (half ? NFEAT : 4); ++f) {
            const int fi = feat_idx[fbase + f];
            const int q = fi / C_FEAT, r = fi - q * C_FEAT;
            const float4 qv = *reinterpret_cast<const float4*>(
                Wq_f + ((size_t)f * NQ_FEAT + q) * EMB_D + oc * 4);
            const float4 rv = *reinterpret_cast<const float4*>(
                Wr_f + ((size_t)f * C_FEAT + r) * EMB_D + oc * 4);
            union { ushort4 v; uint2 u; } pk;
            pk.v.x = f2bf(qv.x * rv.x);
            pk.v.y = f2bf(qv.y * rv.y);
            pk.v.z = f2bf(qv.z * rv.z);
            pk.v.w = f2bf(qv.w * rv.w);
            *reinterpret_cast<uint2*>(&T[row][2 + f][oc * 4]) = pk.u;
        }

        // hist: stage own-parity offsets (wave-internal), gather half items
        const int start = hist_off[br];
        const int end   = (br + 1 < B) ? hist_off[br + 1] : Mtot;
        const int cnt   = end - start;
        const int* hp = hist_idx + start;
        for (int i = half + 2 * oc; i < cnt; i += 32) {
            const int hi = hp[i];
            const int q = hi / C_CAMP;
            soff[row][i] = make_int2(q * EMB_D, (hi - q * C_CAMP) * EMB_D);
        }

        const unsigned short* qb = qcb + oc * 4;
        const unsigned short* rb = rcb + oc * 4;
        float a0 = 0.f, a1 = 0.f, a2 = 0.f, a3 = 0.f;
        #pragma unroll 2
        for (int i = half; i < cnt; i += 2) {
            const int2 o = soff[row][i];
            const uint2 qv = *reinterpret_cast<const uint2*>(qb + o.x);
            const uint2 rv = *reinterpret_cast<const uint2*>(rb + o.y);
            a0 += blo(qv.x) * blo(rv.x);
            a1 += bhi(qv.x) * bhi(rv.x);
            a2 += blo(qv.y) * blo(rv.y);
            a3 += bhi(qv.y) * bhi(rv.y);
        }
        if (half == 1) {
            part[row][oc * 4 + 0] = a0; part[row][oc * 4 + 1] = a1;
            part[row][oc * 4 + 2] = a2; part[row][oc * 4 + 3] = a3;
        }
        __syncthreads();
        if (half == 0) {
            const float inv = 1.f / (float)max(cnt, 1);
            union { ushort4 v; uint2 u; } pk;
            pk.v.x = f2bf((a0 + part[row][oc * 4 + 0]) * inv);
            pk.v.y = f2bf((a1 + part[row][oc * 4 + 1]) * inv);
            pk.v.z = f2bf((a2 + part[row][oc * 4 + 2]) * inv);
            pk.v.w = f2bf((a3 + part[row][oc * 4 + 3]) * inv);
            *reinterpret_cast<uint2*>(&T[row][1][oc * 4]) = pk.u;
        }
    }
    __syncthreads();

    // ---- interactions: 36 pairs x 16 rows ----
    for (int p = t; p < NPAIRS * TROWS; p += 512) {
        const int row = p & (TROWS - 1);
        const int pr  = p / TROWS;
        int i = 0, rem = pr;
        while (rem >= (NROWS - 1) - i) { rem -= (NROWS - 1) - i; ++i; }
        const int j = i + 1 + rem;
        const unsigned short* ti = &T[row][i][0];
        const unsigned short* tj = &T[row][j][0];
        float s = 0.f;
        #pragma unroll
        for (int d = 0; d < EMB_D; d += 4) {
            const uint2 u = *reinterpret_cast<const uint2*>(ti + d);
            const uint2 v = *reinterpret_cast<const uint2*>(tj + d);
            s += blo(u.x) * blo(v.x) + bhi(u.x) * bhi(v.x)
               + blo(u.y) * blo(v.y) + bhi(u.y) * bhi(v.y);
        }
        combs[row][EMB_D + pr] = f2bf(s);
    }
    __syncthreads();

    // ---- proj (waves 0-3): 16x128, K=128 (Wp fp32, K=100 + zero pad) ----
    if (wave < 4) {
        facc4 acc[2] = {};
        #pragma unroll
        for (int kw = 0; kw < 3; ++kw) {
            const bf16x8 af = *reinterpret_cast<const bf16x8*>(
                &combs[fr][kw * 32 + fk * 8]);
            #pragma unroll
            for (int n = 0; n < 2; ++n) {
                const int col = wave * 32 + n * 16 + fr;
                const float* wrow = Wp + (size_t)col * COMB + kw * 32 + fk * 8;
                const float4 w0 = *reinterpret_cast<const float4*>(wrow);
                const float4 w1 = *reinterpret_cast<const float4*>(wrow + 4);
                bfr8 bw;
                bw.u[0] = f2bf(w0.x); bw.u[1] = f2bf(w0.y);
                bw.u[2] = f2bf(w0.z); bw.u[3] = f2bf(w0.w);
                bw.u[4] = f2bf(w1.x); bw.u[5] = f2bf(w1.y);
                bw.u[6] = f2bf(w1.z); bw.u[7] = f2bf(w1.w);
                acc[n] = __builtin_amdgcn_mfma_f32_16x16x32_bf16(af, bw.v, acc[n], 0, 0, 0);
            }
        }
        {   // kw = 3: k = 96..127; Wp cols >= 100 are zero; combs already 0-padded
            const bf16x8 af = *reinterpret_cast<const bf16x8*>(&combs[fr][96 + fk * 8]);
            #pragma unroll
            for (int n = 0; n < 2; ++n) {
                const int col = wave * 32 + n * 16 + fr;
                bfr8 bw;
                #pragma unroll
                for (int j = 0; j < 8; ++j) bw.u[j] = 0;
                if (fk == 0) {
                    const float4 w0 = *reinterpret_cast<const float4*>(
                        Wp + (size_t)col * COMB + 96);
                    bw.u[0] = f2bf(w0.x); bw.u[1] = f2bf(w0.y);
                    bw.u[2] = f2bf(w0.z); bw.u[3] = f2bf(w0.w);
                }
                acc[n] = __builtin_amdgcn_mfma_f32_16x16x32_bf16(af, bw.v, acc[n], 0, 0, 0);
            }
        }
        #pragma unroll
        for (int n = 0; n < 2; ++n) {
            const int col = wave * 32 + n * 16 + fr;
            const float bv = bp[col];
            #pragma unroll
            for (int j = 0; j < 4; ++j) {
                const int row = fk * 4 + j;
                out[(size_t)(r0 + row) * PROJ + col] = acc[n][j] + bv;
            }
        }
    }
}

// ---------------------------------------------------------------------------
extern "C" void kernel_launch(void* const* d_in, const int* in_sizes, int n_in,
                              void* d_out, int out_size, void* d_ws, size_t ws_size,
                              hipStream_t stream)
{
    const float* x        = (const float*)d_in[0];
    const int*   hist_idx = (const int*)  d_in[1];
    const int*   hist_off = (const int*)  d_in[2];
    const int*   feat_idx = (const int*)  d_in[3];
    const float* Wq_c     = (const float*)d_in[4];
    const float* Wr_c     = (const float*)d_in[5];
    const float* Wq_f     = (const float*)d_in[6];
    const float* Wr_f     = (const float*)d_in[7];
    const float* W0       = (const float*)d_in[8];
    const float* b0       = (const float*)d_in[9];
    const float* W1       = (const float*)d_in[10];
    const float* b1       = (const float*)d_in[11];
    const float* W2       = (const float*)d_in[12];
    const float* b2       = (const float*)d_in[13];
    const float* Wp       = (const float*)d_in[14];
    const float* bp       = (const float*)d_in[15];

    const int M    = in_sizes[0] / DENSE_D;   // 16384
    const int Mtot = in_sizes[1];             // B*HIST

    char* w = (char*)d_ws;
    auto take = [&](size_t bytes) { char* p = w; w += (bytes + 255) & ~(size_t)255; return p; };
    unsigned short* h0b = (unsigned short*)take((size_t)M * HIDDEN1 * 2);
    unsigned short* h1b = (unsigned short*)take((size_t)M * HIDDEN2 * 2);
    unsigned short* qcb = (unsigned short*)take(C_CAMP * EMB_D * 2);
    unsigned short* rcb = (unsigned short*)take(C_CAMP * EMB_D * 2);

    // layer 0: 128x128, BK=32, 2x2 waves; A=x fp32, B=W0 fp32 (reg-cast);
    // camp-table cast fused as prologue. grid (128,4) = 512 blocks.
    gemm16<128, 128, 32, 2, 2, true, true, true, true>
        <<<dim3(M / 128, HIDDEN1 / 128), 256, 0, stream>>>(
        x, W0, b0, h0b, M, HIDDEN1, DENSE_D, Wq_c, Wr_c, qcb, rcb);

    // layer 1: 64x128, BK=64, 1x4 waves; A=h0 bf16 (GLD), B=W1 fp32 (reg-cast)
    gemm16<64, 128, 64, 1, 4, true, false, true, false>
        <<<dim3(M / 64, HIDDEN2 / 128), 256, 0, stream>>>(
        h0b, W1, b1, h1b, M, HIDDEN2, HIDDEN1, nullptr, nullptr, nullptr, nullptr);

    // fused tail: 1024 blocks x 16 rows, 8 waves
    tail_fused<<<M / TROWS, 512, 0, stream>>>(
        h1b, W2, b2, hist_idx, hist_off, feat_idx,
        qcb, rcb, Wq_f, Wr_f, Wp, bp, (float*)d_out, M, Mtot);
}

// Round 9
// 88.520 us; speedup vs baseline: 1.1748x; 1.1748x over previous
//
#include <hip/hip_runtime.h>
#include <hip/hip_bf16.h>
#include <stdint.h>

#define DENSE_D 512
#define HIDDEN1 512
#define HIDDEN2 256
#define EMB_D   64
#define NFEAT   7
#define NROWS   9
#define NPAIRS  36
#define COMB    100          // 64 + 36
#define KPROJ   128          // padded K for projection GEMM
#define PROJ    128
#define C_CAMP  1000
#define C_FEAT  316
#define NQ_FEAT 317
#define TROWS   16           // rows per tail block (1 wave per row)

typedef __attribute__((ext_vector_type(8)))  __bf16 bf16x8;
typedef __attribute__((ext_vector_type(8)))  unsigned short ushort8;
typedef __attribute__((ext_vector_type(4)))  float  facc4;

#define GLD_LDS16(gp, lp) __builtin_amdgcn_global_load_lds( \
    (__attribute__((address_space(1))) void*)(gp), \
    (__attribute__((address_space(3))) void*)(lp), 16, 0, 0)

__device__ inline unsigned short f2bf(float f) {
    __hip_bfloat16 h = __float2bfloat16(f);
    return *reinterpret_cast<unsigned short*>(&h);
}
__device__ inline float blo(unsigned int u) { return __uint_as_float(u << 16); }
__device__ inline float bhi(unsigned int u) { return __uint_as_float(u & 0xffff0000u); }
__device__ inline unsigned int pack2(unsigned short lo, unsigned short hi) {
    return (unsigned int)lo | ((unsigned int)hi << 16);
}

// ---------------------------------------------------------------------------
// bf16 MFMA GEMM, 16x16x32 frags: C = act(A @ W^T + bias), bf16 out.
// WM x WN waves; per-wave (BM/WM) x (BN/WN). LDS k-chunk-major [BK/8][R][8].
// A_F32: A fp32, cast to bf16 during reg-staging; else A bf16 via GLD16.
// ---------------------------------------------------------------------------
template<int BM, int BN, int BK, int WM, int WN, bool RELU, bool A_F32>
__global__ __launch_bounds__(WM * WN * 64)
void gemm16(const void* __restrict__ Avoid,
            const unsigned short* __restrict__ W,
            const float* __restrict__ bias,
            unsigned short* __restrict__ Cout,
            int M, int N, int K)
{
    constexpr int THREADS = WM * WN * 64;
    constexpr int MREP    = BM / (WM * 16);
    constexpr int NREP    = BN / (WN * 16);
    constexpr int SUB     = BK / 32;
    constexpr int ACH     = BM * BK / 8;
    constexpr int BCH     = BN * BK / 8;

    __shared__ __align__(16) unsigned short Asm[BK / 8][BM][8];
    __shared__ __align__(16) unsigned short Bsm[BK / 8][BN][8];

    const int tid  = threadIdx.x;
    const int lane = tid & 63;
    const int wave = tid >> 6;
    const int wm   = wave / WN;
    const int wn   = wave % WN;
    const int row0 = blockIdx.x * BM;
    const int col0 = blockIdx.y * BN;
    const int fr   = lane & 15;
    const int fk   = lane >> 4;

    facc4 acc[MREP][NREP] = {};

    for (int k0 = 0; k0 < K; k0 += BK) {
        if (A_F32) {
            const float* Af = (const float*)Avoid;
            #pragma unroll
            for (int it = 0; it < ACH / THREADS; ++it) {
                const int p  = it * THREADS + tid;
                const int r  = p & (BM - 1);
                const int kc = p / BM;
                const float* src = Af + (size_t)(row0 + r) * K + k0 + kc * 8;
                const float4 v0 = *reinterpret_cast<const float4*>(src);
                const float4 v1 = *reinterpret_cast<const float4*>(src + 4);
                ushort8 cv;
                cv[0] = f2bf(v0.x); cv[1] = f2bf(v0.y);
                cv[2] = f2bf(v0.z); cv[3] = f2bf(v0.w);
                cv[4] = f2bf(v1.x); cv[5] = f2bf(v1.y);
                cv[6] = f2bf(v1.z); cv[7] = f2bf(v1.w);
                *reinterpret_cast<ushort8*>(
                    (unsigned short*)(&Asm[0][0][0]) + (size_t)p * 8) = cv;
            }
        } else {
            const unsigned short* Ab = (const unsigned short*)Avoid;
            #pragma unroll
            for (int it = 0; it < ACH / THREADS; ++it) {
                const int p  = it * THREADS + tid;
                const int r  = p & (BM - 1);
                const int kc = p / BM;
                GLD_LDS16(Ab + (size_t)(row0 + r) * K + k0 + kc * 8,
                          (&Asm[0][0][0]) + (size_t)p * 8);
            }
        }
        #pragma unroll
        for (int it = 0; it < BCH / THREADS; ++it) {
            const int p  = it * THREADS + tid;
            const int r  = p & (BN - 1);
            const int kc = p / BN;
            GLD_LDS16(W + (size_t)(col0 + r) * K + k0 + kc * 8,
                      (&Bsm[0][0][0]) + (size_t)p * 8);
        }
        __syncthreads();

        #pragma unroll
        for (int s = 0; s < SUB; ++s) {
            bf16x8 af[MREP], bw[NREP];
            #pragma unroll
            for (int m = 0; m < MREP; ++m)
                af[m] = *reinterpret_cast<const bf16x8*>(
                    &Asm[s * 4 + fk][wm * (MREP * 16) + m * 16 + fr][0]);
            #pragma unroll
            for (int n = 0; n < NREP; ++n)
                bw[n] = *reinterpret_cast<const bf16x8*>(
                    &Bsm[s * 4 + fk][wn * (NREP * 16) + n * 16 + fr][0]);
            #pragma unroll
            for (int m = 0; m < MREP; ++m)
                #pragma unroll
                for (int n = 0; n < NREP; ++n)
                    acc[m][n] = __builtin_amdgcn_mfma_f32_16x16x32_bf16(
                        af[m], bw[n], acc[m][n], 0, 0, 0);
        }
        __syncthreads();
    }

    // C/D layout: col=lane&15, row=(lane>>4)*4+j  [m89/m91-verified]
    #pragma unroll
    for (int n = 0; n < NREP; ++n) {
        const int col = col0 + wn * (NREP * 16) + n * 16 + fr;
        const float bv = bias[col];
        #pragma unroll
        for (int m = 0; m < MREP; ++m) {
            #pragma unroll
            for (int j = 0; j < 4; ++j) {
                const int row = row0 + wm * (MREP * 16) + m * 16 + fk * 4 + j;
                float v = acc[m][n][j] + bv;
                if (RELU) v = fmaxf(v, 0.f);
                Cout[(size_t)row * N + col] = f2bf(v);
            }
        }
    }
}

// ---------------------------------------------------------------------------
// One-shot prep: cast weights/tables to bf16 (NOT x), pad Wp to [128][128].
// ---------------------------------------------------------------------------
__device__ inline void cast_seg(const float* __restrict__ src,
                                unsigned short* __restrict__ dst,
                                int n4, int id, int stride)
{
    for (int i = id; i < n4; i += stride) {
        const float4 v = reinterpret_cast<const float4*>(src)[i];
        ushort4 o;
        o.x = f2bf(v.x); o.y = f2bf(v.y); o.z = f2bf(v.z); o.w = f2bf(v.w);
        reinterpret_cast<ushort4*>(dst)[i] = o;
    }
}

__global__ __launch_bounds__(256)
void prep_all(const float* __restrict__ W0, const float* __restrict__ W1,
              const float* __restrict__ W2, const float* __restrict__ Wp,
              const float* __restrict__ Wq_c, const float* __restrict__ Wr_c,
              const float* __restrict__ Wq_f, const float* __restrict__ Wr_f,
              unsigned short* w0b, unsigned short* w1b, unsigned short* w2b,
              unsigned short* wpb, unsigned short* qcb, unsigned short* rcb,
              unsigned short* qfb, unsigned short* rfb)
{
    const int id = blockIdx.x * blockDim.x + threadIdx.x;
    const int stride = gridDim.x * blockDim.x;
    cast_seg(W0,   w0b, HIDDEN1 * DENSE_D / 4,   id, stride);
    cast_seg(W1,   w1b, HIDDEN2 * HIDDEN1 / 4,   id, stride);
    cast_seg(W2,   w2b, EMB_D * HIDDEN2 / 4,     id, stride);
    cast_seg(Wq_c, qcb, C_CAMP * EMB_D / 4,      id, stride);
    cast_seg(Wr_c, rcb, C_CAMP * EMB_D / 4,      id, stride);
    cast_seg(Wq_f, qfb, NFEAT * NQ_FEAT * EMB_D / 4, id, stride);
    cast_seg(Wr_f, rfb, NFEAT * C_FEAT * EMB_D / 4,  id, stride);
    for (int i = id; i < PROJ * KPROJ; i += stride) {
        const int r = i >> 7, c = i & 127;
        wpb[i] = (c < COMB) ? f2bf(Wp[r * COMB + c]) : (unsigned short)0;
    }
}

// ---------------------------------------------------------------------------
// Fused tail: per block = 16 rows, 1024 threads (16 waves, one wave per row).
//  1) GEMM2 (waves 0-3): dense = h1[16x256] @ W2^T + b2 (direct global frags)
//  2) per-wave: feature embeds (halves split features) + hist gather with
//     offsets in REGISTERS (lane i holds item i), 2 items/iter via shfl
//     broadcast, shfl_xor(32) combine. No LDS offset table, no per-item div.
//  3) 9x9 upper-tri interactions -> combs
//  4) proj (waves 0-7, 16 cols each): out = combs @ Wp^T + bp
// ---------------------------------------------------------------------------
__global__ __launch_bounds__(1024)
void tail_fused(const unsigned short* __restrict__ h1b,
                const unsigned short* __restrict__ w2b,
                const float* __restrict__ b2,
                const int* __restrict__ hist_idx,
                const int* __restrict__ hist_off,
                const int* __restrict__ feat_idx,
                const unsigned short* __restrict__ qcb,
                const unsigned short* __restrict__ rcb,
                const unsigned short* __restrict__ qfb,
                const unsigned short* __restrict__ rfb,
                const unsigned short* __restrict__ wpb,
                const float* __restrict__ bp,
                float* __restrict__ out,
                int B, int Mtot)
{
    const int r0   = blockIdx.x * TROWS;
    const int t    = threadIdx.x;       // 1024
    const int lane = t & 63;
    const int wave = t >> 6;            // 0..15
    const int fr   = lane & 15;
    const int fk   = lane >> 4;

    __shared__ __align__(16) unsigned short T[TROWS][NROWS][68];
    __shared__ __align__(16) unsigned short combs[TROWS][136];

    // ---- 1) GEMM2 (waves 0-3): 16x64, K=256; wave w -> cols w*16..+15 ----
    if (wave < 4) {
        facc4 acc = {};
        const unsigned short* arow = h1b + (size_t)(r0 + fr) * HIDDEN2;
        const unsigned short* brow = w2b + (size_t)(wave * 16 + fr) * HIDDEN2;
        #pragma unroll
        for (int kw = 0; kw < 8; ++kw) {
            const bf16x8 af = *reinterpret_cast<const bf16x8*>(arow + kw * 32 + fk * 8);
            const bf16x8 bw = *reinterpret_cast<const bf16x8*>(brow + kw * 32 + fk * 8);
            acc = __builtin_amdgcn_mfma_f32_16x16x32_bf16(af, bw, acc, 0, 0, 0);
        }
        const int col = wave * 16 + fr;
        const float bv = b2[col];
        #pragma unroll
        for (int j = 0; j < 4; ++j) {
            const int row = fk * 4 + j;
            const unsigned short hv = f2bf(acc[j] + bv);
            T[row][0][col]  = hv;
            combs[row][col] = hv;
        }
    }

    // zero combs[.][100..135]
    for (int p = t; p < TROWS * 18; p += 1024) {
        const int row = p / 18, c = p % 18;
        *reinterpret_cast<unsigned int*>(&combs[row][100 + c * 2]) = 0u;
    }

    // ---- 2) per-wave row: features + hist gather ----
    {
        const int row = wave;            // one wave per row
        const int br  = r0 + row;
        const int h   = lane >> 5;       // half: item parity / feature group
        const int l2  = lane & 31;       // dim pair index (dims 2*l2, 2*l2+1)

        // feature embeddings: half 0 -> f=0..3, half 1 -> f=4..6
        #pragma unroll
        for (int j = 0; j < 4; ++j) {
            const int f = h * 4 + j;
            if (f < NFEAT) {
                const int fi = feat_idx[br * NFEAT + f];
                const int q = fi / C_FEAT, r = fi - q * C_FEAT;
                const unsigned int qv = *reinterpret_cast<const unsigned int*>(
                    qfb + ((size_t)f * NQ_FEAT + q) * EMB_D + 2 * l2);
                const unsigned int rv = *reinterpret_cast<const unsigned int*>(
                    rfb + ((size_t)f * C_FEAT + r) * EMB_D + 2 * l2);
                *reinterpret_cast<unsigned int*>(&T[row][2 + f][2 * l2]) =
                    pack2(f2bf(blo(qv) * blo(rv)), f2bf(bhi(qv) * bhi(rv)));
            }
        }

        // hist offsets -> registers (lane i holds item i; cnt <= 64)
        const int start = hist_off[br];
        const int end   = (br + 1 < B) ? hist_off[br + 1] : Mtot;
        const int cnt   = end - start;
        int qo = 0, ro = 0;
        if (lane < cnt) {
            const int hi = hist_idx[start + lane];
            const int qq = hi / C_CAMP;
            qo = qq * EMB_D;
            ro = (hi - qq * C_CAMP) * EMB_D;
        }

        // gather: 2 items per iteration (halves), shfl broadcast of offsets
        float a0 = 0.f, a1 = 0.f;
        const int nit = (cnt + 1) >> 1;
        for (int i = 0; i < nit; ++i) {
            const int idx = 2 * i + h;
            const int qoi = __shfl(qo, idx);
            const int roi = __shfl(ro, idx);
            const unsigned int uq = *reinterpret_cast<const unsigned int*>(
                qcb + qoi + 2 * l2);
            const unsigned int ur = *reinterpret_cast<const unsigned int*>(
                rcb + roi + 2 * l2);
            if (idx < cnt) {
                a0 += blo(uq) * blo(ur);
                a1 += bhi(uq) * bhi(ur);
            }
        }
        a0 += __shfl_xor(a0, 32);
        a1 += __shfl_xor(a1, 32);
        if (h == 0) {
            const float inv = 1.f / (float)max(cnt, 1);
            *reinterpret_cast<unsigned int*>(&T[row][1][2 * l2]) =
                pack2(f2bf(a0 * inv), f2bf(a1 * inv));
        }
    }
    __syncthreads();

    // ---- 3) interactions: 36 pairs x 16 rows = 576 tasks ----
    for (int p = t; p < NPAIRS * TROWS; p += 1024) {
        const int row = p & (TROWS - 1);
        const int pr  = p / TROWS;
        int i = 0, rem = pr;
        while (rem >= (NROWS - 1) - i) { rem -= (NROWS - 1) - i; ++i; }
        const int j = i + 1 + rem;
        const unsigned short* ti = &T[row][i][0];
        const unsigned short* tj = &T[row][j][0];
        float s = 0.f;
        #pragma unroll
        for (int d = 0; d < EMB_D; d += 4) {
            const uint2 u = *reinterpret_cast<const uint2*>(ti + d);
            const uint2 v = *reinterpret_cast<const uint2*>(tj + d);
            s += blo(u.x) * blo(v.x) + bhi(u.x) * bhi(v.x)
               + blo(u.y) * blo(v.y) + bhi(u.y) * bhi(v.y);
        }
        combs[row][EMB_D + pr] = f2bf(s);
    }
    __syncthreads();

    // ---- 4) proj (waves 0-7): 16x128, K=128; wave w -> cols w*16..+15 ----
    if (wave < 8) {
        facc4 acc = {};
        #pragma unroll
        for (int kw = 0; kw < 4; ++kw) {
            const bf16x8 af = *reinterpret_cast<const bf16x8*>(
                &combs[fr][kw * 32 + fk * 8]);
            const bf16x8 bw = *reinterpret_cast<const bf16x8*>(
                wpb + (size_t)(wave * 16 + fr) * KPROJ + kw * 32 + fk * 8);
            acc = __builtin_amdgcn_mfma_f32_16x16x32_bf16(af, bw, acc, 0, 0, 0);
        }
        const int col = wave * 16 + fr;
        const float bv = bp[col];
        #pragma unroll
        for (int j = 0; j < 4; ++j) {
            const int row = fk * 4 + j;
            out[(size_t)(r0 + row) * PROJ + col] = acc[j] + bv;
        }
    }
}

// ---------------------------------------------------------------------------
extern "C" void kernel_launch(void* const* d_in, const int* in_sizes, int n_in,
                              void* d_out, int out_size, void* d_ws, size_t ws_size,
                              hipStream_t stream)
{
    const float* x        = (const float*)d_in[0];
    const int*   hist_idx = (const int*)  d_in[1];
    const int*   hist_off = (const int*)  d_in[2];
    const int*   feat_idx = (const int*)  d_in[3];
    const float* Wq_c     = (const float*)d_in[4];
    const float* Wr_c     = (const float*)d_in[5];
    const float* Wq_f     = (const float*)d_in[6];
    const float* Wr_f     = (const float*)d_in[7];
    const float* W0       = (const float*)d_in[8];
    const float* b0       = (const float*)d_in[9];
    const float* W1       = (const float*)d_in[10];
    const float* b1       = (const float*)d_in[11];
    const float* W2       = (const float*)d_in[12];
    const float* b2       = (const float*)d_in[13];
    const float* Wp       = (const float*)d_in[14];
    const float* bp       = (const float*)d_in[15];

    const int M    = in_sizes[0] / DENSE_D;   // 16384
    const int Mtot = in_sizes[1];             // B*HIST

    char* w = (char*)d_ws;
    auto take = [&](size_t bytes) { char* p = w; w += (bytes + 255) & ~(size_t)255; return p; };
    unsigned short* w0b = (unsigned short*)take(HIDDEN1 * DENSE_D * 2);
    unsigned short* w1b = (unsigned short*)take(HIDDEN2 * HIDDEN1 * 2);
    unsigned short* w2b = (unsigned short*)take(EMB_D * HIDDEN2 * 2);
    unsigned short* wpb = (unsigned short*)take(PROJ * KPROJ * 2);
    unsigned short* qcb = (unsigned short*)take(C_CAMP * EMB_D * 2);
    unsigned short* rcb = (unsigned short*)take(C_CAMP * EMB_D * 2);
    unsigned short* qfb = (unsigned short*)take(NFEAT * NQ_FEAT * EMB_D * 2);
    unsigned short* rfb = (unsigned short*)take(NFEAT * C_FEAT * EMB_D * 2);
    unsigned short* h0b = (unsigned short*)take((size_t)M * HIDDEN1 * 2);
    unsigned short* h1b = (unsigned short*)take((size_t)M * HIDDEN2 * 2);

    prep_all<<<256, 256, 0, stream>>>(W0, W1, W2, Wp, Wq_c, Wr_c, Wq_f, Wr_f,
                                      w0b, w1b, w2b, wpb, qcb, rcb, qfb, rfb);

    // layer 0: m97 shape 128x128, BK=32, 2x2 waves, fused fp32->bf16 A staging.
    gemm16<128, 128, 32, 2, 2, true, true>
        <<<dim3(M / 128, HIDDEN1 / 128), 256, 0, stream>>>(
        x, w0b, b0, h0b, M, HIDDEN1, DENSE_D);

    // layer 1: 64x128, BK=64, 1x4 waves, A bf16 GLD.
    gemm16<64, 128, 64, 1, 4, true, false>
        <<<dim3(M / 64, HIDDEN2 / 128), 256, 0, stream>>>(
        h0b, w1b, b1, h1b, M, HIDDEN2, HIDDEN1);

    // fused tail: 1024 blocks x 16 rows, 16 waves (1 wave per row)
    tail_fused<<<M / TROWS, 1024, 0, stream>>>(
        h1b, w2b, b2, hist_idx, hist_off, feat_idx,
        qcb, rcb, qfb, rfb, wpb, bp, (float*)d_out, M, Mtot);
}